// Round 1
// baseline (220.309 us; speedup 1.0000x reference)
//
#include <hip/hip_runtime.h>
#include <stdint.h>

#define BM 128
#define BN 128
#define BK 32

typedef __bf16 bf16_t;
typedef __attribute__((ext_vector_type(8))) __bf16 bf16x8;
typedef __attribute__((ext_vector_type(4))) float f32x4;

// ---- fp32 -> bf16 (RNE) ----
__device__ __forceinline__ unsigned short f2bf(float f) {
    unsigned u = __float_as_uint(f);
    u += 0x7FFF + ((u >> 16) & 1);
    return (unsigned short)(u >> 16);
}

__global__ __launch_bounds__(256)
void f32_to_bf16_k(const float* __restrict__ in, unsigned short* __restrict__ out, int n4) {
    int i = blockIdx.x * blockDim.x + threadIdx.x;
    int stride = gridDim.x * blockDim.x;
    for (; i < n4; i += stride) {
        float4 v = reinterpret_cast<const float4*>(in)[i];
        ushort4 o;
        o.x = f2bf(v.x); o.y = f2bf(v.y); o.z = f2bf(v.z); o.w = f2bf(v.w);
        reinterpret_cast<ushort4*>(out)[i] = o;
    }
}

// ---- async global -> LDS, 16B per lane ----
__device__ __forceinline__ void gload16(const unsigned short* g, unsigned short* l) {
    __builtin_amdgcn_global_load_lds(
        (const __attribute__((address_space(1))) unsigned int*)g,
        (__attribute__((address_space(3))) unsigned int*)l, 16, 0, 0);
}

// ---- generic NT GEMM: C[m,n] = scale * sum_k A[m,k]*B[n,k] ----
// A: [M,K] bf16 row-major (lda), B: [N,K] bf16 row-major (ldb)
// CT: unsigned short (bf16 out) or float
// TRI: skip blocks with bc > br (causal scores)
// KLIM: limit k-loop to (br+1)*BM (causal PV; P has zeros above diagonal)
template <typename CT, bool TRI, bool KLIM>
__global__ __launch_bounds__(256, 2)
void gemm_nt(const unsigned short* __restrict__ A, const unsigned short* __restrict__ B,
             CT* __restrict__ C, int lda, int ldb, int ldc, int K,
             long long sA, long long sB, long long sC, float scale)
{
    int br = blockIdx.y, bc = blockIdx.x;
    if (TRI && bc > br) return;
    A += (long long)blockIdx.z * sA;
    B += (long long)blockIdx.z * sB;
    C += (long long)blockIdx.z * sC;

    int kmax = K;
    if (KLIM) { int kl = (br + 1) * BM; kmax = kl < K ? kl : K; }

    __shared__ unsigned short As[BM][BK];
    __shared__ unsigned short Bs[BN][BK];

    int t    = threadIdx.x;
    int lane = t & 63;
    int wid  = t >> 6;
    int wm   = wid >> 1, wn = wid & 1;

    f32x4 acc[4][4];
#pragma unroll
    for (int m = 0; m < 4; ++m)
#pragma unroll
        for (int n = 0; n < 4; ++n) acc[m][n] = (f32x4){0.f, 0.f, 0.f, 0.f};

    const int m0 = br * BM, n0 = bc * BN;
    const int rsel = lane & 15;
    const int ksel = (lane >> 4) * 8;

    int nk = kmax / BK;
    for (int kt = 0; kt < nk; ++kt) {
        int k0 = kt * BK;
        // stage A(128x32) and B(128x32): 2 x 16B per thread each
#pragma unroll
        for (int i = 0; i < 2; ++i) {
            int c   = t + i * 256;       // 16B-chunk index
            int row = c >> 2;            // 4 chunks per 32-elem row
            int ke  = (c & 3) * 8;
            gload16(A + (long long)(m0 + row) * lda + k0 + ke, &As[row][ke]);
            gload16(B + (long long)(n0 + row) * ldb + k0 + ke, &Bs[row][ke]);
        }
        __syncthreads();   // compiler drains vmcnt before barrier

        bf16x8 af[4], bfr[4];
#pragma unroll
        for (int m = 0; m < 4; ++m)
            af[m] = *reinterpret_cast<const bf16x8*>(&As[wm * 64 + m * 16 + rsel][ksel]);
#pragma unroll
        for (int n = 0; n < 4; ++n)
            bfr[n] = *reinterpret_cast<const bf16x8*>(&Bs[wn * 64 + n * 16 + rsel][ksel]);

#pragma unroll
        for (int m = 0; m < 4; ++m)
#pragma unroll
            for (int n = 0; n < 4; ++n)
                acc[m][n] = __builtin_amdgcn_mfma_f32_16x16x32_bf16(af[m], bfr[n], acc[m][n], 0, 0, 0);
        __syncthreads();
    }

    // epilogue: D[row][col], col = lane&15, row = (lane>>4)*4 + i  (m89-verified)
    const int rowl = (lane >> 4) * 4;
    const int coll = lane & 15;
#pragma unroll
    for (int m = 0; m < 4; ++m) {
#pragma unroll
        for (int n = 0; n < 4; ++n) {
#pragma unroll
            for (int i = 0; i < 4; ++i) {
                int r = m0 + wm * 64 + m * 16 + rowl + i;
                int c = n0 + wn * 64 + n * 16 + coll;
                float v = acc[m][n][i] * scale;
                if constexpr (sizeof(CT) == 2)
                    ((unsigned short*)C)[(long long)r * ldc + c] = f2bf(v);
                else
                    ((float*)C)[(long long)r * ldc + c] = v;
            }
        }
    }
}

// ---- causal row softmax: reads fp32 scores (only k<=q), writes bf16 P (zeros for k>q) ----
__device__ __forceinline__ float waveMax(float v) {
#pragma unroll
    for (int o = 32; o > 0; o >>= 1) v = fmaxf(v, __shfl_xor(v, o, 64));
    return v;
}
__device__ __forceinline__ float waveSum(float v) {
#pragma unroll
    for (int o = 32; o > 0; o >>= 1) v += __shfl_xor(v, o, 64);
    return v;
}

__global__ __launch_bounds__(256)
void softmax_causal(const float* __restrict__ S, unsigned short* __restrict__ P, int Slen) {
    long long row = blockIdx.x;                 // b*Slen + q
    int q = (int)(row % Slen);
    const float* srow = S + row * Slen;
    unsigned short* prow = P + row * Slen;
    int len = q + 1;
    int t = threadIdx.x;
    __shared__ float red[4];

    float mx = -3.0e38f;
    for (int k = t; k < len; k += 256) mx = fmaxf(mx, srow[k]);
    mx = waveMax(mx);
    if ((t & 63) == 0) red[t >> 6] = mx;
    __syncthreads();
    mx = fmaxf(fmaxf(red[0], red[1]), fmaxf(red[2], red[3]));

    float sum = 0.f;
    for (int k = t; k < len; k += 256) sum += __expf(srow[k] - mx);
    sum = waveSum(sum);
    __syncthreads();
    if ((t & 63) == 0) red[t >> 6] = sum;
    __syncthreads();
    sum = red[0] + red[1] + red[2] + red[3];
    float inv = 1.0f / sum;

    for (int k = t; k < Slen; k += 256) {
        unsigned short o = 0;
        if (k < len) o = f2bf(__expf(srow[k] - mx) * inv);
        prow[k] = o;
    }
}

extern "C" void kernel_launch(void* const* d_in, const int* in_sizes, int n_in,
                              void* d_out, int out_size, void* d_ws, size_t ws_size,
                              hipStream_t stream) {
    const int B = 4, S = 2048, D = 1024;
    const float* X  = (const float*)d_in[0];
    const float* Wq = (const float*)d_in[1];
    const float* Wk = (const float*)d_in[2];
    const float* Wv = (const float*)d_in[3];
    float* out = (float*)d_out;

    char* ws = (char*)d_ws;
    unsigned short* Xb  = (unsigned short*)ws; ws += (size_t)B * S * D * 2;
    unsigned short* Wqb = (unsigned short*)ws; ws += (size_t)D * D * 2;
    unsigned short* Wkb = (unsigned short*)ws; ws += (size_t)D * D * 2;
    unsigned short* Wvb = (unsigned short*)ws; ws += (size_t)D * D * 2;
    unsigned short* Qb  = (unsigned short*)ws; ws += (size_t)B * S * D * 2;
    unsigned short* Kb  = (unsigned short*)ws; ws += (size_t)B * S * D * 2;
    unsigned short* Vt  = (unsigned short*)ws; ws += (size_t)B * S * D * 2;  // [b][e][k]
    float*          Sc  = (float*)ws;          ws += (size_t)B * S * S * 4;
    unsigned short* P   = (unsigned short*)ws; ws += (size_t)B * S * S * 2;

    // 1) convert inputs to bf16
    f32_to_bf16_k<<<2048, 256, 0, stream>>>(X,  Xb,  B * S * D / 4);
    f32_to_bf16_k<<<512,  256, 0, stream>>>(Wq, Wqb, D * D / 4);
    f32_to_bf16_k<<<512,  256, 0, stream>>>(Wk, Wkb, D * D / 4);
    f32_to_bf16_k<<<512,  256, 0, stream>>>(Wv, Wvb, D * D / 4);

    dim3 blk(256);
    // 2) Q = Xb @ Wq^T  [8192,1024]
    gemm_nt<unsigned short, false, false><<<dim3(D / BN, B * S / BM, 1), blk, 0, stream>>>(
        Xb, Wqb, Qb, D, D, D, D, 0, 0, 0, 1.0f);
    //    K = Xb @ Wk^T
    gemm_nt<unsigned short, false, false><<<dim3(D / BN, B * S / BM, 1), blk, 0, stream>>>(
        Xb, Wkb, Kb, D, D, D, D, 0, 0, 0, 1.0f);
    //    Vt[b] = Wv @ Xb[b]^T  -> Vt[b][e][k] = V[b][k][e], per-batch, M=D, N=S
    gemm_nt<unsigned short, false, false><<<dim3(S / BN, D / BM, B), blk, 0, stream>>>(
        Wvb, Xb, Vt, D, D, S, D, 0, (long long)S * D, (long long)D * S, 1.0f);

    // 3) scores[b] = (Q K^T) / 32, lower-triangle blocks only, fp32
    gemm_nt<float, true, false><<<dim3(S / BN, S / BM, B), blk, 0, stream>>>(
        Qb, Kb, Sc, D, D, S, D, (long long)S * D, (long long)S * D, (long long)S * S, 0.03125f);

    // 4) causal softmax -> bf16 P (zeros above diagonal)
    softmax_causal<<<B * S, 256, 0, stream>>>(Sc, P, S);

    // 5) out[b] = P @ Vt^T, k-loop limited per block-row
    gemm_nt<float, false, true><<<dim3(D / BN, S / BM, B), blk, 0, stream>>>(
        P, Vt, out, S, S, D, S, (long long)S * S, (long long)D * S, (long long)S * D, 1.0f);
}

// Round 2
// 194.854 us; speedup vs baseline: 1.1306x; 1.1306x over previous
//
#include <hip/hip_runtime.h>
#include <stdint.h>

#define BM 128
#define BN 128
#define BK 32

typedef __attribute__((ext_vector_type(8))) __bf16 bf16x8;
typedef __attribute__((ext_vector_type(4))) float f32x4;

// ---- fp32 -> bf16 (RNE) ----
__device__ __forceinline__ unsigned short f2bf(float f) {
    unsigned u = __float_as_uint(f);
    u += 0x7FFF + ((u >> 16) & 1);
    return (unsigned short)(u >> 16);
}

__global__ __launch_bounds__(256)
void f32_to_bf16_k(const float* __restrict__ in, unsigned short* __restrict__ out, int n4) {
    int i = blockIdx.x * blockDim.x + threadIdx.x;
    int stride = gridDim.x * blockDim.x;
    for (; i < n4; i += stride) {
        float4 v = reinterpret_cast<const float4*>(in)[i];
        ushort4 o;
        o.x = f2bf(v.x); o.y = f2bf(v.y); o.z = f2bf(v.z); o.w = f2bf(v.w);
        reinterpret_cast<ushort4*>(out)[i] = o;
    }
}

// convert the three D*D weights in one dispatch (blockIdx.y selects source)
__global__ __launch_bounds__(256)
void w_convert_k(const float* __restrict__ Wq, const float* __restrict__ Wk,
                 const float* __restrict__ Wv, unsigned short* __restrict__ out, int n4) {
    const float* src = blockIdx.y == 0 ? Wq : (blockIdx.y == 1 ? Wk : Wv);
    unsigned short* dst = out + (size_t)blockIdx.y * n4 * 4;
    int i = blockIdx.x * blockDim.x + threadIdx.x;
    int stride = gridDim.x * blockDim.x;
    for (; i < n4; i += stride) {
        float4 v = reinterpret_cast<const float4*>(src)[i];
        ushort4 o;
        o.x = f2bf(v.x); o.y = f2bf(v.y); o.z = f2bf(v.z); o.w = f2bf(v.w);
        reinterpret_cast<ushort4*>(dst)[i] = o;
    }
}

// ---- async global -> LDS, 16B per lane ----
__device__ __forceinline__ void gload16(const unsigned short* g, unsigned short* l) {
    __builtin_amdgcn_global_load_lds(
        (const __attribute__((address_space(1))) unsigned int*)g,
        (__attribute__((address_space(3))) unsigned int*)l, 16, 0, 0);
}

// ---- generic NT GEMM, 2-phase prefetch double-buffer ----
// C[m,n] = scale * sum_k A[m,k]*B[n,k]
// A: [M,K] bf16 row-major (lda), B: [N,K] bf16 row-major (ldb)
// TRI: skip blocks with bc > br (causal scores)
// KLIM: limit k-loop to (br+1)*BM (causal PV)
template <typename CT, bool TRI, bool KLIM>
__global__ __launch_bounds__(256, 2)
void gemm_nt(const unsigned short* __restrict__ A, const unsigned short* __restrict__ B,
             CT* __restrict__ C, int lda, int ldb, int ldc, int K,
             long long sA, long long sB, long long sC, float scale)
{
    int br = blockIdx.y, bc = blockIdx.x;
    if (TRI && bc > br) return;
    A += (long long)blockIdx.z * sA;
    B += (long long)blockIdx.z * sB;
    C += (long long)blockIdx.z * sC;

    int kmax = K;
    if (KLIM) { int kl = (br + 1) * BM; kmax = kl < K ? kl : K; }

    __shared__ unsigned short As[2][BM * BK];
    __shared__ unsigned short Bs[2][BN * BK];

    int t    = threadIdx.x;
    int lane = t & 63;
    int wid  = t >> 6;
    int wm   = wid >> 1, wn = wid & 1;

    f32x4 acc[4][4];
#pragma unroll
    for (int m = 0; m < 4; ++m)
#pragma unroll
        for (int n = 0; n < 4; ++n) acc[m][n] = (f32x4){0.f, 0.f, 0.f, 0.f};

    const int m0 = br * BM, n0 = bc * BN;
    const int rsel = lane & 15;
    const int ksel = (lane >> 4) * 8;
    const int srow = t >> 2;          // staging row for this thread (chunk 0)
    const int ske  = (t & 3) * 8;     // staging k-element offset

    // stage tile kt into buffer buf (2 x 16B per thread for A and B each)
    auto stage = [&](int buf, int kt) {
        int k0 = kt * BK;
#pragma unroll
        for (int i = 0; i < 2; ++i) {
            int row = srow + i * 64;
            gload16(A + (long long)(m0 + row) * lda + k0 + ske, &As[buf][row * BK + ske]);
            gload16(B + (long long)(n0 + row) * ldb + k0 + ske, &Bs[buf][row * BK + ske]);
        }
    };

    auto compute = [&](int buf) {
        bf16x8 af[4], bfr[4];
#pragma unroll
        for (int m = 0; m < 4; ++m)
            af[m] = *reinterpret_cast<const bf16x8*>(&As[buf][(wm * 64 + m * 16 + rsel) * BK + ksel]);
#pragma unroll
        for (int n = 0; n < 4; ++n)
            bfr[n] = *reinterpret_cast<const bf16x8*>(&Bs[buf][(wn * 64 + n * 16 + rsel) * BK + ksel]);
#pragma unroll
        for (int m = 0; m < 4; ++m)
#pragma unroll
            for (int n = 0; n < 4; ++n)
                acc[m][n] = __builtin_amdgcn_mfma_f32_16x16x32_bf16(af[m], bfr[n], acc[m][n], 0, 0, 0);
    };

    int nk = kmax / BK;
    stage(0, 0);
    __syncthreads();
    for (int kt = 0; kt < nk; kt += 2) {
        if (kt + 1 < nk) stage(1, kt + 1);   // prefetch overlaps compute below
        compute(0);
        __syncthreads();                      // drains vmcnt; buf1 now ready
        if (kt + 1 < nk) {
            if (kt + 2 < nk) stage(0, kt + 2);
            compute(1);
            __syncthreads();
        }
    }

    // epilogue: D[row][col], col = lane&15, row = (lane>>4)*4 + i  (m89-verified)
    const int rowl = (lane >> 4) * 4;
    const int coll = lane & 15;
#pragma unroll
    for (int m = 0; m < 4; ++m) {
#pragma unroll
        for (int n = 0; n < 4; ++n) {
#pragma unroll
            for (int i = 0; i < 4; ++i) {
                int r = m0 + wm * 64 + m * 16 + rowl + i;
                int c = n0 + wn * 64 + n * 16 + coll;
                float v = acc[m][n][i] * scale;
                if constexpr (sizeof(CT) == 2)
                    ((unsigned short*)C)[(long long)r * ldc + c] = f2bf(v);
                else
                    ((float*)C)[(long long)r * ldc + c] = v;
            }
        }
    }
}

// ---- causal row softmax ----
__device__ __forceinline__ float waveMax(float v) {
#pragma unroll
    for (int o = 32; o > 0; o >>= 1) v = fmaxf(v, __shfl_xor(v, o, 64));
    return v;
}
__device__ __forceinline__ float waveSum(float v) {
#pragma unroll
    for (int o = 32; o > 0; o >>= 1) v += __shfl_xor(v, o, 64);
    return v;
}

__global__ __launch_bounds__(256)
void softmax_causal(const float* __restrict__ S, unsigned short* __restrict__ P, int Slen) {
    __shared__ float e[2048];
    __shared__ float red[4];
    long long row = blockIdx.x;                 // b*Slen + q
    int q = (int)(row % Slen);
    const float* srow = S + row * Slen;
    unsigned short* prow = P + row * Slen;
    int len  = q + 1;
    int wlim = ((q >> 7) + 1) << 7;             // PV never reads past roundup(len,128)
    int t = threadIdx.x;

    float mx = -3.0e38f;
    for (int k = t; k < len; k += 256) mx = fmaxf(mx, srow[k]);
    mx = waveMax(mx);
    if ((t & 63) == 0) red[t >> 6] = mx;
    __syncthreads();
    mx = fmaxf(fmaxf(red[0], red[1]), fmaxf(red[2], red[3]));

    float sum = 0.f;
    for (int k = t; k < len; k += 256) {
        float v = __expf(srow[k] - mx);
        e[k] = v;
        sum += v;
    }
    sum = waveSum(sum);
    __syncthreads();
    if ((t & 63) == 0) red[t >> 6] = sum;
    __syncthreads();
    sum = red[0] + red[1] + red[2] + red[3];
    float inv = 1.0f / sum;

    for (int k = t; k < wlim; k += 256)
        prow[k] = (k < len) ? f2bf(e[k] * inv) : (unsigned short)0;
}

extern "C" void kernel_launch(void* const* d_in, const int* in_sizes, int n_in,
                              void* d_out, int out_size, void* d_ws, size_t ws_size,
                              hipStream_t stream) {
    const int B = 4, S = 2048, D = 1024;
    const float* X  = (const float*)d_in[0];
    const float* Wq = (const float*)d_in[1];
    const float* Wk = (const float*)d_in[2];
    const float* Wv = (const float*)d_in[3];
    float* out = (float*)d_out;

    char* ws = (char*)d_ws;
    unsigned short* Xb  = (unsigned short*)ws; ws += (size_t)B * S * D * 2;
    unsigned short* Wqb = (unsigned short*)ws; ws += (size_t)D * D * 2;  // Wq,Wk,Wv contiguous
    unsigned short* Wkb = (unsigned short*)ws; ws += (size_t)D * D * 2;
    unsigned short* Wvb = (unsigned short*)ws; ws += (size_t)D * D * 2;
    unsigned short* Qb  = (unsigned short*)ws; ws += (size_t)B * S * D * 2;  // Q,K contiguous
    unsigned short* Kb  = (unsigned short*)ws; ws += (size_t)B * S * D * 2;
    unsigned short* Vt  = (unsigned short*)ws; ws += (size_t)B * S * D * 2;  // [b][e][k]
    float*          Sc  = (float*)ws;          ws += (size_t)B * S * S * 4;
    unsigned short* P   = (unsigned short*)ws; ws += (size_t)B * S * S * 2;

    // 1) convert inputs to bf16
    f32_to_bf16_k<<<2048, 256, 0, stream>>>(X, Xb, B * S * D / 4);
    w_convert_k<<<dim3(512, 3), 256, 0, stream>>>(Wq, Wk, Wv, Wqb, D * D / 4);

    dim3 blk(256);
    // 2) Q and K in ONE dispatch (z selects weight/output; strides D*D / B*S*D)
    gemm_nt<unsigned short, false, false><<<dim3(D / BN, B * S / BM, 2), blk, 0, stream>>>(
        Xb, Wqb, Qb, D, D, D, D, 0, (long long)D * D, (long long)B * S * D, 1.0f);
    //    Vt[b] = Wv @ Xb[b]^T  -> Vt[b][e][k] = V[b][k][e]
    gemm_nt<unsigned short, false, false><<<dim3(S / BN, D / BM, B), blk, 0, stream>>>(
        Wvb, Xb, Vt, D, D, S, D, 0, (long long)S * D, (long long)D * S, 1.0f);

    // 3) scores[b] = (Q K^T) / 32, lower-triangle blocks only, fp32
    gemm_nt<float, true, false><<<dim3(S / BN, S / BM, B), blk, 0, stream>>>(
        Qb, Kb, Sc, D, D, S, D, (long long)S * D, (long long)S * D, (long long)S * S, 0.03125f);

    // 4) causal softmax -> bf16 P (zeros up to block boundary)
    softmax_causal<<<B * S, 256, 0, stream>>>(Sc, P, S);

    // 5) out[b] = P @ Vt^T, k-loop limited per block-row
    gemm_nt<float, false, true><<<dim3(D / BN, S / BM, B), blk, 0, stream>>>(
        P, Vt, out, S, S, D, S, (long long)S * S, (long long)D * S, (long long)S * D, 1.0f);
}

// Round 3
// 184.407 us; speedup vs baseline: 1.1947x; 1.0567x over previous
//
#include <hip/hip_runtime.h>
#include <stdint.h>

typedef __attribute__((ext_vector_type(8))) __bf16 bf16x8;
typedef __attribute__((ext_vector_type(4))) float f32x4;

// ---- fp32 -> bf16 (RNE) ----
__device__ __forceinline__ unsigned short f2bf(float f) {
    unsigned u = __float_as_uint(f);
    u += 0x7FFF + ((u >> 16) & 1);
    return (unsigned short)(u >> 16);
}

__global__ __launch_bounds__(256)
void f32_to_bf16_k(const float* __restrict__ in, unsigned short* __restrict__ out, int n4) {
    int i = blockIdx.x * blockDim.x + threadIdx.x;
    int stride = gridDim.x * blockDim.x;
    for (; i < n4; i += stride) {
        float4 v = reinterpret_cast<const float4*>(in)[i];
        ushort4 o;
        o.x = f2bf(v.x); o.y = f2bf(v.y); o.z = f2bf(v.z); o.w = f2bf(v.w);
        reinterpret_cast<ushort4*>(out)[i] = o;
    }
}

__global__ __launch_bounds__(256)
void w_convert_k(const float* __restrict__ Wq, const float* __restrict__ Wk,
                 const float* __restrict__ Wv, unsigned short* __restrict__ out, int n4) {
    const float* src = blockIdx.y == 0 ? Wq : (blockIdx.y == 1 ? Wk : Wv);
    unsigned short* dst = out + (size_t)blockIdx.y * n4 * 4;
    int i = blockIdx.x * blockDim.x + threadIdx.x;
    int stride = gridDim.x * blockDim.x;
    for (; i < n4; i += stride) {
        float4 v = reinterpret_cast<const float4*>(src)[i];
        ushort4 o;
        o.x = f2bf(v.x); o.y = f2bf(v.y); o.z = f2bf(v.z); o.w = f2bf(v.w);
        reinterpret_cast<ushort4*>(dst)[i] = o;
    }
}

__device__ __forceinline__ void gload16(const unsigned short* g, unsigned short* l) {
    __builtin_amdgcn_global_load_lds(
        (const __attribute__((address_space(1))) unsigned int*)g,
        (__attribute__((address_space(3))) unsigned int*)l, 16, 0, 0);
}

// ============ deep-pipelined NT GEMM (BK=64, 512 thr, counted vmcnt, swizzled LDS) ============
// C[m,n] = scale * sum_k A[m,k]*B[n,k];  A:[M,K] row-major bf16, B:[N,K] row-major bf16.
// LDS holds [rows][64] bf16 tiles; within each 128B row, 16B chunk cc is stored at
// chunk (cc ^ (row&7))  -- applied on the GLOBAL source address (LDS dest stays linear
// for global_load_lds), and again on the ds_read address (involution).
template <int BM, int BN, int WM, int WN, typename CT, bool TRI, bool KLIM>
__global__ __launch_bounds__(512, 2)
void gemm8(const unsigned short* __restrict__ A, const unsigned short* __restrict__ B,
           CT* __restrict__ C, int lda, int ldb, int ldc, int K,
           long long sA, long long sB, long long sC, float scale)
{
    constexpr int FM  = BM / WM / 16;            // M-frags per wave
    constexpr int FN  = BN / WN / 16;            // N-frags per wave
    constexpr int ACH = BM * 8;                  // A chunks (16B) per tile
    constexpr int LPT = (BM + BN) * 64 * 2 / (512 * 16);  // gloads per thread per tile

    int br = blockIdx.y, bc = blockIdx.x;
    if (TRI && bc > br) return;
    A += (long long)blockIdx.z * sA;
    B += (long long)blockIdx.z * sB;
    C += (long long)blockIdx.z * sC;

    int kmax = K;
    if (KLIM) { int kl = (br + 1) * BM; kmax = kl < K ? kl : K; }

    __shared__ unsigned short As[2][BM * 64];
    __shared__ unsigned short Bs[2][BN * 64];

    const int t    = threadIdx.x;
    const int lane = t & 63;
    const int wid  = t >> 6;
    const int wm   = wid / WN;
    const int wn   = wid % WN;
    const int m0   = br * BM, n0 = bc * BN;
    const int rsel = lane & 15;
    const int gsel = lane >> 4;                  // 0..3

    f32x4 acc[FM][FN];
#pragma unroll
    for (int m = 0; m < FM; ++m)
#pragma unroll
        for (int n = 0; n < FN; ++n) acc[m][n] = (f32x4){0.f, 0.f, 0.f, 0.f};

    auto stage = [&](int buf, int kt) {
        const int k0 = kt * 64;
#pragma unroll
        for (int i = 0; i < LPT; ++i) {
            int ci = i * 512 + t;
            if (ci < ACH) {
                int row = ci >> 3, cc = ci & 7;
                gload16(A + (long long)(m0 + row) * lda + k0 + ((cc ^ (row & 7)) * 8),
                        &As[buf][ci * 8]);
            } else {
                int cj = ci - ACH;
                int row = cj >> 3, cc = cj & 7;
                gload16(B + (long long)(n0 + row) * ldb + k0 + ((cc ^ (row & 7)) * 8),
                        &Bs[buf][cj * 8]);
            }
        }
    };

    const int nk = kmax / 64;
    stage(0, 0);

    for (int kt = 0; kt < nk; ++kt) {
        const int c = kt & 1;
        // all waves finished reading buf c^1 (previous tile) -> safe to overwrite
        __builtin_amdgcn_s_barrier();
        __builtin_amdgcn_sched_barrier(0);
        if (kt + 1 < nk) {
            stage(c ^ 1, kt + 1);                 // next tile's loads stay in flight
            if constexpr (LPT == 8) asm volatile("s_waitcnt vmcnt(8)" ::: "memory");
            else                    asm volatile("s_waitcnt vmcnt(6)" ::: "memory");
        } else {
            asm volatile("s_waitcnt vmcnt(0)" ::: "memory");
        }
        __builtin_amdgcn_s_barrier();             // everyone's tile-kt loads landed
        __builtin_amdgcn_sched_barrier(0);

        // B fragments for the whole tile (held across phases)
        bf16x8 bfr[FN][2];
#pragma unroll
        for (int n = 0; n < FN; ++n)
#pragma unroll
            for (int ks = 0; ks < 2; ++ks) {
                int rb = wn * (FN * 16) + n * 16 + rsel;
                int cc = ks * 4 + gsel;
                bfr[n][ks] = *reinterpret_cast<const bf16x8*>(
                    &Bs[c][rb * 64 + ((cc ^ (rb & 7)) * 8)]);
            }

        bf16x8 afP[2][2], afQ[2][2];
        {
#pragma unroll
            for (int mm = 0; mm < 2; ++mm)
#pragma unroll
                for (int ks = 0; ks < 2; ++ks) {
                    int r  = wm * (FM * 16) + mm * 16 + rsel;
                    int cc = ks * 4 + gsel;
                    afP[mm][ks] = *reinterpret_cast<const bf16x8*>(
                        &As[c][r * 64 + ((cc ^ (r & 7)) * 8)]);
                }
        }
#pragma unroll
        for (int p = 0; p < FM / 2; ++p) {
            bf16x8(&cur)[2][2] = (p & 1) ? afQ : afP;
            bf16x8(&nxt)[2][2] = (p & 1) ? afP : afQ;
            if (p + 1 < FM / 2) {
#pragma unroll
                for (int mm = 0; mm < 2; ++mm)
#pragma unroll
                    for (int ks = 0; ks < 2; ++ks) {
                        int r  = wm * (FM * 16) + (2 * (p + 1) + mm) * 16 + rsel;
                        int cc = ks * 4 + gsel;
                        nxt[mm][ks] = *reinterpret_cast<const bf16x8*>(
                            &As[c][r * 64 + ((cc ^ (r & 7)) * 8)]);
                    }
            }
            __builtin_amdgcn_s_setprio(1);
#pragma unroll
            for (int mm = 0; mm < 2; ++mm)
#pragma unroll
                for (int n = 0; n < FN; ++n)
#pragma unroll
                    for (int ks = 0; ks < 2; ++ks)
                        acc[2 * p + mm][n] = __builtin_amdgcn_mfma_f32_16x16x32_bf16(
                            cur[mm][ks], bfr[n][ks], acc[2 * p + mm][n], 0, 0, 0);
            __builtin_amdgcn_s_setprio(0);
        }
    }

    // epilogue: D[row][col], col = lane&15, row = (lane>>4)*4 + i  (m89-verified)
    const int rowl = (lane >> 4) * 4;
#pragma unroll
    for (int m = 0; m < FM; ++m) {
#pragma unroll
        for (int n = 0; n < FN; ++n) {
#pragma unroll
            for (int i = 0; i < 4; ++i) {
                int r = m0 + wm * (FM * 16) + m * 16 + rowl + i;
                int cI = n0 + wn * (FN * 16) + n * 16 + rsel;
                float v = acc[m][n][i] * scale;
                if constexpr (sizeof(CT) == 2)
                    ((unsigned short*)C)[(long long)r * ldc + cI] = f2bf(v);
                else
                    ((float*)C)[(long long)r * ldc + cI] = v;
            }
        }
    }
}

// ---- causal row softmax ----
__device__ __forceinline__ float waveMax(float v) {
#pragma unroll
    for (int o = 32; o > 0; o >>= 1) v = fmaxf(v, __shfl_xor(v, o, 64));
    return v;
}
__device__ __forceinline__ float waveSum(float v) {
#pragma unroll
    for (int o = 32; o > 0; o >>= 1) v += __shfl_xor(v, o, 64);
    return v;
}

__global__ __launch_bounds__(256)
void softmax_causal(const float* __restrict__ S, unsigned short* __restrict__ P, int Slen) {
    __shared__ float e[2048];
    __shared__ float red[4];
    long long row = blockIdx.x;                 // b*Slen + q
    int q = (int)(row % Slen);
    const float* srow = S + row * Slen;
    unsigned short* prow = P + row * Slen;
    int len  = q + 1;
    int wlim = ((q >> 8) + 1) << 8;             // zero-fill to 256-aligned boundary (PV BM<=256)
    int t = threadIdx.x;

    float mx = -3.0e38f;
    for (int k = t; k < len; k += 256) mx = fmaxf(mx, srow[k]);
    mx = waveMax(mx);
    if ((t & 63) == 0) red[t >> 6] = mx;
    __syncthreads();
    mx = fmaxf(fmaxf(red[0], red[1]), fmaxf(red[2], red[3]));

    float sum = 0.f;
    for (int k = t; k < len; k += 256) {
        float v = __expf(srow[k] - mx);
        e[k] = v;
        sum += v;
    }
    sum = waveSum(sum);
    __syncthreads();
    if ((t & 63) == 0) red[t >> 6] = sum;
    __syncthreads();
    sum = red[0] + red[1] + red[2] + red[3];
    float inv = 1.0f / sum;

    for (int k = t; k < wlim; k += 256)
        prow[k] = (k < len) ? f2bf(e[k] * inv) : (unsigned short)0;
}

extern "C" void kernel_launch(void* const* d_in, const int* in_sizes, int n_in,
                              void* d_out, int out_size, void* d_ws, size_t ws_size,
                              hipStream_t stream) {
    const int B = 4, S = 2048, D = 1024;
    const float* X  = (const float*)d_in[0];
    const float* Wq = (const float*)d_in[1];
    const float* Wk = (const float*)d_in[2];
    const float* Wv = (const float*)d_in[3];
    float* out = (float*)d_out;

    char* ws = (char*)d_ws;
    unsigned short* Xb  = (unsigned short*)ws; ws += (size_t)B * S * D * 2;
    unsigned short* Wqb = (unsigned short*)ws; ws += (size_t)D * D * 2;  // Wq,Wk,Wv contiguous
    unsigned short* Wkb = (unsigned short*)ws; ws += (size_t)D * D * 2;
    unsigned short* Wvb = (unsigned short*)ws; ws += (size_t)D * D * 2;
    unsigned short* Qb  = (unsigned short*)ws; ws += (size_t)B * S * D * 2;  // Q,K contiguous
    unsigned short* Kb  = (unsigned short*)ws; ws += (size_t)B * S * D * 2;
    unsigned short* Vt  = (unsigned short*)ws; ws += (size_t)B * S * D * 2;  // [b][e][k]
    float*          Sc  = (float*)ws;          ws += (size_t)B * S * S * 4;
    unsigned short* P   = (unsigned short*)ws; ws += (size_t)B * S * S * 2;

    f32_to_bf16_k<<<2048, 256, 0, stream>>>(X, Xb, B * S * D / 4);
    w_convert_k<<<dim3(512, 3), 256, 0, stream>>>(Wq, Wk, Wv, Wqb, D * D / 4);

    dim3 blk(512);
    // Q and K in one dispatch: 256x256 tiles, grid (1024/256, 8192/256, 2) = 256 blocks
    gemm8<256, 256, 2, 4, unsigned short, false, false>
        <<<dim3(D / 256, B * S / 256, 2), blk, 0, stream>>>(
        Xb, Wqb, Qb, D, D, D, D, 0, (long long)D * D, (long long)B * S * D, 1.0f);

    // Vt[b] = Wv @ Xb[b]^T : 128x256 tiles, grid (2048/256, 1024/128, 4) = 256 blocks
    gemm8<128, 256, 1, 8, unsigned short, false, false>
        <<<dim3(S / 256, D / 128, B), blk, 0, stream>>>(
        Wvb, Xb, Vt, D, D, S, D, 0, (long long)S * D, (long long)D * S, 1.0f);

    // scores = (Q K^T)/32, lower-triangle 256x256 blocks, fp32: grid (8,8,4), TRI
    gemm8<256, 256, 2, 4, float, true, false>
        <<<dim3(S / 256, S / 256, B), blk, 0, stream>>>(
        Qb, Kb, Sc, D, D, S, D, (long long)S * D, (long long)S * D, (long long)S * S, 0.03125f);

    softmax_causal<<<B * S, 256, 0, stream>>>(Sc, P, S);

    // out = P @ Vt^T : 128x256 tiles, grid (1024/256, 2048/128, 4) = 256 blocks, KLIM
    gemm8<128, 256, 1, 8, float, false, true>
        <<<dim3(D / 256, S / 128, B), blk, 0, stream>>>(
        P, Vt, out, S, S, D, S, (long long)S * S, (long long)D * S, (long long)S * D, 1.0f);
}